// Round 7
// baseline (429.732 us; speedup 1.0000x reference)
//
#include <hip/hip_runtime.h>
#include <hip/hip_bf16.h>
#include <stdint.h>

// Encoder pipeline, activations token-major [T=32768, C] bf16.
// im2col(K=256 pad) -> convGEMM(+b0,prelu) -> 3x { GEMM(+b, fused col-stats) ->
// bnfold -> bnact(prelu[, +pos,prelu am on layer3]) } -> mixGEMM(+bm, fp32, perm-scatter)
//
// GEMM: 256x256 block, BK=64, 8 waves (2M x 4N) of 128x64 wave tiles, 4-phase
// schedule per K-tile (sync/staging skeleton identical to rounds 5/6, verified).
// NEW: register-level read pipelining — each phase issues the ds_reads for the
// NEXT phase before its barrier; MFMA consumes regs loaded a phase earlier, so
// LDS data-return overlaps the MFMA cluster. Frag regs: aX/aY (A, rotating),
// b0f/b1f (B per kk). Compiler emits counted lgkmcnt waits automatically.
//   ph1: rd aX=A(0,0), b0f=B(k0) [own]; rd aY=A(1,0) [pre]; stageA h0; bar; MFMA(aX,b0f,mh0); bar
//   ph2: rd aX=A(0,1), b1f=B(k1) [pre]; stageA h1;           bar; MFMA(aY,b0f,mh1); bar
//   ph3: rd aY=A(1,1) [pre];                                 bar; MFMA(aX,b1f,mh0); bar
//   ph4: stageB(t+2) x2; vmcnt(4);                           bar; MFMA(aY,b1f,mh1); bar
// ws: B0(64MB) | B1(64MB) | part(1MB,2MB rsvd) | scsh(8KB) | inv(128KB) | wbuf(2MB)

typedef __attribute__((ext_vector_type(8))) short bf16x8;
typedef __attribute__((ext_vector_type(4))) float f32x4;

__device__ __forceinline__ float bf2f(uint32_t u) {
  union { uint32_t i; float f; } v; v.i = u << 16; return v.f;
}
__device__ __forceinline__ ushort f2bf(float f) {
  union { float f; uint32_t i; } v; v.f = f;
  uint32_t i = v.i;
  return (ushort)((i + 0x7FFFu + ((i >> 16) & 1u)) >> 16);
}

// ---------------------------------------------------------------- GEMM
// Out[t,d] = sum_k A[t,k] * Bw[d,k]  (bf16, K-contiguous), fp32 accum.
// LDS [2][256][64] K-major per operand, XOR chunk swizzle (slot = chunk ^ (row&7));
// staged via global_load_lds with inverse-swizzled global source (both-sides rule).
// 1-D grid, XCD-grouping swizzle: 2^XB d-blocks sharing an A-slab run on one XCD.
// EPI: 0 = bias+prelu -> bf16
//      1 = bias -> bf16, + per-256-row-slab column sum/sumsq partials into `part`
//      2 = bias -> fp32, rows scattered via inverse permutation (mixer)
template<int EPI, int XB, int K, int DOUT>
__global__ void __launch_bounds__(512, 2)
gemm_kernel(const ushort* __restrict__ A, const ushort* __restrict__ Bw,
            const float* __restrict__ bias, const float* __restrict__ alpha,
            void* __restrict__ outp, float* __restrict__ part,
            const int* __restrict__ inv)
{
  __shared__ __align__(16) ushort At[2][256 * 64];
  __shared__ __align__(16) ushort Bt[2][256 * 64];
  const int tid  = threadIdx.x;
  const int lane = tid & 63;
  const int wid  = tid >> 6;      // 0..7
  const int wm   = wid >> 2;      // 0..1  (M half: 128 rows)
  const int wn   = wid & 3;       // 0..3  (N quarter: 64 cols)

  // XCD-grouping swizzle: s = ((y>>3)*NX + x)*8 + (y&7)
  const int s = blockIdx.x;
  const int j = s >> 3;
  const int x = j & ((1 << XB) - 1);
  const int y = ((j >> XB) << 3) | (s & 7);
  const int t0 = y << 8;
  const int d0 = x << 8;

  f32x4 acc[8][4] = {};

  // ---- hoisted LDS read bases (byte offsets; swizzle term lane-constant) ----
  const int swz = (((lane >> 4) ^ (lane & 7)) << 4);     // kk=0 swizzle bytes
  const char* LA0 = (const char*)&At[0][0] + ((((wm << 7) + (lane & 15))) << 7) + swz;
  const char* LA1 = (const char*)&At[0][0] + ((((wm << 7) + (lane & 15))) << 7) + (swz ^ 64);
  const char* LB0 = (const char*)&Bt[0][0] + ((((wn << 6) + (lane & 15))) << 7) + swz;
  const char* LB1 = (const char*)&Bt[0][0] + ((((wn << 6) + (lane & 15))) << 7) + (swz ^ 64);

  // ---- hoisted staging bases ----
  const int lrow8 = lane >> 3;             // row within 8-row staging group
  const int csrc  = (lane & 7) ^ lrow8;    // inverse-swizzled source chunk
  const ushort* gAw = A  + (size_t)(t0 + (wid << 4) + lrow8) * K + (csrc << 3);
  const ushort* gBw = Bw + (size_t)(d0 + (wid << 4) + lrow8) * K + (csrc << 3);
  char* stA = (char*)&At[0][0] + (wid << 11);   // wave-uniform LDS dest base
  char* stB = (char*)&Bt[0][0] + (wid << 11);

#define STAGE_A(T, BUF, H) do {                                                          \
    __builtin_amdgcn_global_load_lds(                                                    \
      (const __attribute__((address_space(1))) uint32_t*)(gAw + (size_t)((H)*128)*K + ((size_t)(T) << 6)),     \
      (__attribute__((address_space(3))) uint32_t*)(stA + (BUF)*32768 + (H)*16384), 16, 0, 0);                  \
    __builtin_amdgcn_global_load_lds(                                                    \
      (const __attribute__((address_space(1))) uint32_t*)(gAw + (size_t)((H)*128+8)*K + ((size_t)(T) << 6)),   \
      (__attribute__((address_space(3))) uint32_t*)(stA + (BUF)*32768 + (H)*16384 + 1024), 16, 0, 0);           \
  } while (0)
#define STAGE_B(T, BUF, H) do {                                                          \
    __builtin_amdgcn_global_load_lds(                                                    \
      (const __attribute__((address_space(1))) uint32_t*)(gBw + (size_t)((H)*128)*K + ((size_t)(T) << 6)),     \
      (__attribute__((address_space(3))) uint32_t*)(stB + (BUF)*32768 + (H)*16384), 16, 0, 0);                  \
    __builtin_amdgcn_global_load_lds(                                                    \
      (const __attribute__((address_space(1))) uint32_t*)(gBw + (size_t)((H)*128+8)*K + ((size_t)(T) << 6)),   \
      (__attribute__((address_space(3))) uint32_t*)(stB + (BUF)*32768 + (H)*16384 + 1024), 16, 0, 0);           \
  } while (0)

#define RD_A(dst, BASE, CUR, MH) do {                                                    \
    dst[0] = *(const bf16x8*)((BASE) + (CUR)*32768 + (MH)*8192 + 0);                     \
    dst[1] = *(const bf16x8*)((BASE) + (CUR)*32768 + (MH)*8192 + 2048);                  \
    dst[2] = *(const bf16x8*)((BASE) + (CUR)*32768 + (MH)*8192 + 4096);                  \
    dst[3] = *(const bf16x8*)((BASE) + (CUR)*32768 + (MH)*8192 + 6144);                  \
  } while (0)
#define RD_B(dst, BASE, CUR) do {                                                        \
    dst[0] = *(const bf16x8*)((BASE) + (CUR)*32768 + 0);                                 \
    dst[1] = *(const bf16x8*)((BASE) + (CUR)*32768 + 2048);                              \
    dst[2] = *(const bf16x8*)((BASE) + (CUR)*32768 + 4096);                              \
    dst[3] = *(const bf16x8*)((BASE) + (CUR)*32768 + 6144);                              \
  } while (0)
#define MFMA16(AF, BF, MH) do {                                                          \
    __builtin_amdgcn_s_setprio(1);                                                       \
    _Pragma("unroll")                                                                    \
    for (int m_ = 0; m_ < 4; ++m_)                                                       \
      _Pragma("unroll")                                                                  \
      for (int n_ = 0; n_ < 4; ++n_)                                                     \
        acc[((MH) << 2) + m_][n_] = __builtin_amdgcn_mfma_f32_16x16x32_bf16(             \
            AF[m_], BF[n_], acc[((MH) << 2) + m_][n_], 0, 0, 0);                         \
    __builtin_amdgcn_s_setprio(0);                                                       \
  } while (0)

  // ph1 MFMA: aX,b0f | ph2: aY,b0f | ph3: aX,b1f | ph4: aY,b1f
#define TILE_BODY(T, CUR, HN1, HN2) do {                                                 \
    /* ph1: own-reads for this phase + prefetch A(1,0) */                                \
    RD_A(aX, LA0, CUR, 0);                                                               \
    RD_B(b0f, LB0, CUR);                                                                 \
    RD_A(aY, LA0, CUR, 1);                                                               \
    if (HN1) STAGE_A((T) + 1, (CUR) ^ 1, 0);                                             \
    __builtin_amdgcn_s_barrier();                                                        \
    MFMA16(aX, b0f, 0);                                                                  \
    __builtin_amdgcn_s_barrier();                                                        \
    /* ph2: prefetch A(0,1), B(k1) */                                                    \
    RD_A(aX, LA1, CUR, 0);                                                               \
    RD_B(b1f, LB1, CUR);                                                                 \
    if (HN1) STAGE_A((T) + 1, (CUR) ^ 1, 1);                                             \
    __builtin_amdgcn_s_barrier();                                                        \
    MFMA16(aY, b0f, 1);                                                                  \
    __builtin_amdgcn_s_barrier();                                                        \
    /* ph3: prefetch A(1,1) */                                                           \
    RD_A(aY, LA1, CUR, 1);                                                               \
    __builtin_amdgcn_s_barrier();                                                        \
    MFMA16(aX, b1f, 0);                                                                  \
    __builtin_amdgcn_s_barrier();                                                        \
    /* ph4: stage B(t+2) + counted gate */                                               \
    if (HN2) { STAGE_B((T) + 2, CUR, 0); STAGE_B((T) + 2, CUR, 1); }                     \
    if (HN2)      { asm volatile("s_waitcnt vmcnt(4)" ::: "memory"); }                   \
    else if (HN1) { asm volatile("s_waitcnt vmcnt(0)" ::: "memory"); }                   \
    __builtin_amdgcn_s_barrier();                                                        \
    MFMA16(aY, b1f, 1);                                                                  \
    __builtin_amdgcn_s_barrier();                                                        \
  } while (0)

  constexpr int NT = K >> 6;   // even (256/1024 -> 4/16)

  // prologue: tile0 fully, tile1 B-halves (A of tile1 staged during tile0 ph1/2)
  STAGE_A(0, 0, 0); STAGE_A(0, 0, 1);
  STAGE_B(0, 0, 0); STAGE_B(0, 0, 1);
  STAGE_B(1, 1, 0); STAGE_B(1, 1, 1);
  asm volatile("s_waitcnt vmcnt(4)" ::: "memory");
  __builtin_amdgcn_s_barrier();

  bf16x8 aX[4], aY[4], b0f[4], b1f[4];

#pragma unroll 1
  for (int tp = 0; tp < NT; tp += 2) {
    const bool more = (tp + 2 < NT);
    TILE_BODY(tp,     0, true, more);
    TILE_BODY(tp + 1, 1, more, more);
  }

  // epilogue: C/D layout col = lane&15, row = (lane>>4)*4 + reg
  // m-outer / n-inner so the 4 chunks of each 128B line issue back-to-back.
  float bs[4];
#pragma unroll
  for (int n = 0; n < 4; ++n) bs[n] = bias[d0 + (wn << 6) + (n << 4) + (lane & 15)];
  float a0v = (EPI == 0) ? alpha[0] : 0.0f;
  float sA[4] = {0.f, 0.f, 0.f, 0.f}, s2A[4] = {0.f, 0.f, 0.f, 0.f};

#pragma unroll
  for (int m = 0; m < 8; ++m) {
#pragma unroll
    for (int r = 0; r < 4; ++r) {
      int row = t0 + (wm << 7) + (m << 4) + ((lane >> 4) << 2) + r;
      int orow = (EPI == 2) ? ((row & ~255) | inv[row]) : row;
#pragma unroll
      for (int n = 0; n < 4; ++n) {
        int d = d0 + (wn << 6) + (n << 4) + (lane & 15);
        float v = acc[m][n][r] + bs[n];
        if (EPI == 0) v = v > 0.f ? v : a0v * v;
        if (EPI == 1) { sA[n] += v; s2A[n] += v * v; }
        if (EPI == 2) ((float*)outp)[(size_t)orow * DOUT + d] = v;
        else          ((ushort*)outp)[(size_t)row * DOUT + d] = f2bf(v);
      }
    }
  }

  if (EPI == 1) {
    // deterministic per-block column reduction (256 cols), one slab row of partials.
    float2* sm = (float2*)&At[0][0];            // 8 x 256 float2 = 16KB
    int slot = (wm << 2) | (lane >> 4);         // 0..7
    __syncthreads();
#pragma unroll
    for (int n = 0; n < 4; ++n) {
      int c = (wn << 6) + (n << 4) + (lane & 15);
      sm[slot * 256 + c] = make_float2(sA[n], s2A[n]);
    }
    __syncthreads();
    if (tid < 256) {
      float ss = 0.f, ss2 = 0.f;
      for (int q = 0; q < 8; ++q) {
        float2 v = sm[q * 256 + tid];
        ss += v.x; ss2 += v.y;
      }
      part[(size_t)y * 2048 + d0 + tid]        = ss;
      part[(size_t)y * 2048 + 1024 + d0 + tid] = ss2;
    }
  }
#undef STAGE_A
#undef STAGE_B
#undef RD_A
#undef RD_B
#undef MFMA16
#undef TILE_BODY
}

// ------------------------------------------------------------ BN fold
__global__ void bnfold_kernel(const float* __restrict__ part, const float* __restrict__ g,
                              const float* __restrict__ bt, float* __restrict__ scsh) {
  int d = (blockIdx.x << 8) + threadIdx.x;    // grid 4
  float s = 0.f, s2 = 0.f;
  for (int j = 0; j < 128; ++j) { s += part[j * 2048 + d]; s2 += part[j * 2048 + 1024 + d]; }
  float mean = s * (1.f / 32768.f);
  float var  = s2 * (1.f / 32768.f) - mean * mean;
  float sc = g[d] * rsqrtf(var + 1e-5f);
  scsh[d] = sc;
  scsh[1024 + d] = bt[d] - mean * sc;
}

// y = prelu(y*sc + sh, p) [+ pos, prelu am], in place, 8 bf16/thread
template<bool MIX>
__global__ void bnact_kernel(ushort* __restrict__ Y, const float* __restrict__ scsh,
                             const float* __restrict__ p, const float* __restrict__ pos,
                             const float* __restrict__ am) {
  size_t i = (((size_t)blockIdx.x << 8) + threadIdx.x) << 3;
  int d = (int)(i & 1023);
  float pp = p[0];
  float aa = MIX ? am[0] : 0.f;
  float pv[8];
  if (MIX) {
    int prow = (int)((i >> 10) & 255);
    const float4* pb = (const float4*)(pos + ((size_t)prow << 10) + d);
    float4 pA = pb[0], pB = pb[1];
    pv[0]=pA.x; pv[1]=pA.y; pv[2]=pA.z; pv[3]=pA.w;
    pv[4]=pB.x; pv[5]=pB.y; pv[6]=pB.z; pv[7]=pB.w;
  }
  uint4 raw = *(const uint4*)(Y + i);
  uint32_t w[4] = {raw.x, raw.y, raw.z, raw.w};
  uint32_t o[4];
#pragma unroll
  for (int q = 0; q < 4; ++q) {
    int dd = d + q * 2;
    float v0 = bf2f(w[q] & 0xFFFFu) * scsh[dd]     + scsh[1024 + dd];
    float v1 = bf2f(w[q] >> 16)     * scsh[dd + 1] + scsh[1024 + dd + 1];
    v0 = v0 > 0.f ? v0 : pp * v0;
    v1 = v1 > 0.f ? v1 : pp * v1;
    if (MIX) {
      v0 += pv[2 * q];     v1 += pv[2 * q + 1];
      v0 = v0 > 0.f ? v0 : aa * v0;
      v1 = v1 > 0.f ? v1 : aa * v1;
    }
    o[q] = (uint32_t)f2bf(v0) | ((uint32_t)f2bf(v1) << 16);
  }
  *(uint4*)(Y + i) = make_uint4(o[0], o[1], o[2], o[3]);
}

// inverse permutation: inv[b, perm[b,i]] = i
__global__ void invperm_kernel(const int* __restrict__ perm, int* __restrict__ inv) {
  int t = (blockIdx.x << 8) + threadIdx.x;    // 32768
  inv[(t & ~255) + perm[t]] = t & 255;
}

// ----------------------------------------------------------- preprocessing
__global__ void f2b_kernel(const float* __restrict__ in, ushort* __restrict__ out, int n) {
  int i = (blockIdx.x << 8) + threadIdx.x;
  if (i < n) out[i] = f2bf(in[i]);
}

__global__ void padw0_kernel(const float* __restrict__ w0, ushort* __restrict__ o) {
  int d = blockIdx.x, j = threadIdx.x;  // 1024 x 256
  o[d * 256 + j] = (j < 147) ? f2bf(w0[d * 147 + j]) : (ushort)0;
}

// patch im2col (K padded to 256): P[t][j=cin*49+dy*7+dx] = x[b,cin,7pi+dy,7pj+dx]
__global__ void im2col_kernel(const float* __restrict__ x, ushort* __restrict__ P) {
  int t = blockIdx.x;        // 32768
  int j = threadIdx.x;       // 256
  ushort v = 0;
  if (j < 147) {
    int b = t >> 8, pidx = t & 255;
    int pi = pidx >> 4, pj = pidx & 15;
    int cin = j / 49, rem = j - cin * 49;
    int dy = rem / 7, dx = rem - dy * 7;
    v = f2bf(x[(size_t)(b * 3 + cin) * 12544 + (size_t)(pi * 7 + dy) * 112 + (pj * 7 + dx)]);
  }
  P[(size_t)t * 256 + j] = v;
}

extern "C" void kernel_launch(void* const* d_in, const int* in_sizes, int n_in,
                              void* d_out, int out_size, void* d_ws, size_t ws_size,
                              hipStream_t stream) {
  const float* x   = (const float*)d_in[0];
  const float* w0  = (const float*)d_in[1];
  const float* b0  = (const float*)d_in[2];
  const float* a0  = (const float*)d_in[3];
  const float* w1  = (const float*)d_in[4];
  const float* b1  = (const float*)d_in[5];
  const float* g1  = (const float*)d_in[6];
  const float* bt1 = (const float*)d_in[7];
  const float* p1  = (const float*)d_in[8];
  const float* w2  = (const float*)d_in[9];
  const float* b2  = (const float*)d_in[10];
  const float* g2  = (const float*)d_in[11];
  const float* bt2 = (const float*)d_in[12];
  const float* p2  = (const float*)d_in[13];
  const float* w3  = (const float*)d_in[14];
  const float* b3  = (const float*)d_in[15];
  const float* g3  = (const float*)d_in[16];
  const float* bt3 = (const float*)d_in[17];
  const float* p3  = (const float*)d_in[18];
  const float* pos = (const float*)d_in[19];
  const float* am  = (const float*)d_in[20];
  const float* wm  = (const float*)d_in[21];
  const float* bm  = (const float*)d_in[22];
  const int*  perm = (const int*)d_in[23];

  char* ws = (char*)d_ws;
  ushort* B0   = (ushort*)ws;                                   // 64MB
  ushort* B1   = (ushort*)(ws + 67108864);                      // 64MB
  float*  part = (float*)(ws + 134217728);                      // 128*2048*4 = 1MB (2MB rsvd)
  float*  scsh = (float*)(ws + 134217728 + 2097152);            // 8KB
  int*    inv  = (int*)  (ws + 134217728 + 2097152 + 8192);     // 128KB
  ushort* wbuf = (ushort*)(ws + 134217728 + 2097152 + 8192 + 131072); // 2MB

  invperm_kernel<<<dim3(128), dim3(256), 0, stream>>>(perm, inv);
  im2col_kernel<<<dim3(32768), dim3(256), 0, stream>>>(x, B1);
  padw0_kernel<<<dim3(1024), dim3(256), 0, stream>>>(w0, wbuf);

  // patch-embed conv as GEMM: P(B1) x w0^T -> act0(B0), bias+prelu  (K=256)
  gemm_kernel<0, 2, 256, 1024><<<dim3(512), dim3(512), 0, stream>>>(
      B1, wbuf, b0, a0, (void*)B0, nullptr, nullptr);

  // layer 1: B0 -> B1  (stats fused)
  f2b_kernel<<<dim3(4096), dim3(256), 0, stream>>>(w1, wbuf, 1048576);
  gemm_kernel<1, 2, 1024, 1024><<<dim3(512), dim3(512), 0, stream>>>(
      B0, wbuf, b1, nullptr, (void*)B1, part, nullptr);
  bnfold_kernel<<<dim3(4), dim3(256), 0, stream>>>(part, g1, bt1, scsh);
  bnact_kernel<false><<<dim3(16384), dim3(256), 0, stream>>>(B1, scsh, p1, nullptr, nullptr);

  // layer 2: B1 -> B0
  f2b_kernel<<<dim3(4096), dim3(256), 0, stream>>>(w2, wbuf, 1048576);
  gemm_kernel<1, 2, 1024, 1024><<<dim3(512), dim3(512), 0, stream>>>(
      B1, wbuf, b2, nullptr, (void*)B0, part, nullptr);
  bnfold_kernel<<<dim3(4), dim3(256), 0, stream>>>(part, g2, bt2, scsh);
  bnact_kernel<false><<<dim3(16384), dim3(256), 0, stream>>>(B0, scsh, p2, nullptr, nullptr);

  // layer 3: B0 -> B1, bnact fused with +pos & prelu(am)
  f2b_kernel<<<dim3(4096), dim3(256), 0, stream>>>(w3, wbuf, 1048576);
  gemm_kernel<1, 2, 1024, 1024><<<dim3(512), dim3(512), 0, stream>>>(
      B0, wbuf, b3, nullptr, (void*)B1, part, nullptr);
  bnfold_kernel<<<dim3(4), dim3(256), 0, stream>>>(part, g3, bt3, scsh);
  bnact_kernel<true><<<dim3(16384), dim3(256), 0, stream>>>(B1, scsh, p3, pos, am);

  // mixer: out = (enc @ wm^T + bm) rows scattered via inv -> d_out (fp32)
  f2b_kernel<<<dim3(2048), dim3(256), 0, stream>>>(wm, wbuf, 524288);
  gemm_kernel<2, 1, 1024, 512><<<dim3(256), dim3(512), 0, stream>>>(
      B1, wbuf, bm, nullptr, d_out, nullptr, inv);
}

// Round 8
// 394.195 us; speedup vs baseline: 1.0902x; 1.0902x over previous
//
#include <hip/hip_runtime.h>
#include <hip/hip_bf16.h>
#include <stdint.h>

// Encoder pipeline, activations token-major [T=32768, C] bf16.
// im2col(K=256 pad) -> convGEMM(+b0,prelu) -> 3x { GEMM(+b, fused col-stats) ->
// bnfold -> bnact(prelu[, +pos,prelu am on layer3]) } -> mixGEMM(+bm, fp32, perm-scatter)
//
// GEMM: 256x256 block, BK=64, 8 waves (2M x 4N) of 128x64 wave tiles.
// TWO barriers per K-tile (waves drift -> LDS/MFMA pipes overlap via TLP):
//   gate(t): vmcnt(4) [tile t landed; B(t+1) stays in flight]; barrier
//   ph1: rd A(mh0,k0)+B(k0); stage A(t+1)->buf^1 (safe: all buf^1 readers of
//        tile t-1 returned before their gate arrival); MFMA(mh0,k0)
//   ph2: rd A(mh1,k0); MFMA(mh1,k0)
//   ph3: rd A(mh0,k1)+B(k1); MFMA(mh0,k1)   [b1f consumed -> all B reads returned]
//   mid-barrier; stage B(t+2)->buf[cur].B (disjoint from A-region read in ph4)
//   ph4: rd A(mh1,k1); MFMA(mh1,k1)
// vmcnt queue at gate(t): [... A(t)@t-1.ph1, B(t+1)@t-1.mid] -> vmcnt(4) waits
// A(t)+older (incl B(t)), leaves B(t+1) in flight. Last tile: vmcnt(0).
// ws: B0(64MB) | B1(64MB) | part(1MB,2MB rsvd) | scsh(8KB) | inv(128KB) | wbuf(2MB)

typedef __attribute__((ext_vector_type(8))) short bf16x8;
typedef __attribute__((ext_vector_type(4))) float f32x4;

__device__ __forceinline__ float bf2f(uint32_t u) {
  union { uint32_t i; float f; } v; v.i = u << 16; return v.f;
}
__device__ __forceinline__ ushort f2bf(float f) {
  union { float f; uint32_t i; } v; v.f = f;
  uint32_t i = v.i;
  return (ushort)((i + 0x7FFFu + ((i >> 16) & 1u)) >> 16);
}

// ---------------------------------------------------------------- GEMM
// Out[t,d] = sum_k A[t,k] * Bw[d,k]  (bf16, K-contiguous), fp32 accum.
// LDS [2][256][64] K-major per operand, XOR chunk swizzle (slot = chunk ^ (row&7));
// staged via global_load_lds with inverse-swizzled global source (both-sides rule).
// 1-D grid, XCD-grouping swizzle: 2^XB d-blocks sharing an A-slab run on one XCD.
// EPI: 0 = bias+prelu -> bf16
//      1 = bias -> bf16, + per-256-row-slab column sum/sumsq partials into `part`
//      2 = bias -> fp32, rows scattered via inverse permutation (mixer)
template<int EPI, int XB, int K, int DOUT>
__global__ void __launch_bounds__(512, 2)
gemm_kernel(const ushort* __restrict__ A, const ushort* __restrict__ Bw,
            const float* __restrict__ bias, const float* __restrict__ alpha,
            void* __restrict__ outp, float* __restrict__ part,
            const int* __restrict__ inv)
{
  __shared__ __align__(16) ushort At[2][256 * 64];
  __shared__ __align__(16) ushort Bt[2][256 * 64];
  const int tid  = threadIdx.x;
  const int lane = tid & 63;
  const int wid  = tid >> 6;      // 0..7
  const int wm   = wid >> 2;      // 0..1  (M half: 128 rows)
  const int wn   = wid & 3;       // 0..3  (N quarter: 64 cols)

  // XCD-grouping swizzle: s = ((y>>3)*NX + x)*8 + (y&7)
  const int s = blockIdx.x;
  const int j = s >> 3;
  const int x = j & ((1 << XB) - 1);
  const int y = ((j >> XB) << 3) | (s & 7);
  const int t0 = y << 8;
  const int d0 = x << 8;

  f32x4 acc[8][4] = {};

  // ---- hoisted LDS read bases (byte offsets; swizzle term lane-constant) ----
  const int swz = (((lane >> 4) ^ (lane & 7)) << 4);     // kk=0 swizzle bytes
  const char* LA0 = (const char*)&At[0][0] + ((((wm << 7) + (lane & 15))) << 7) + swz;
  const char* LA1 = (const char*)&At[0][0] + ((((wm << 7) + (lane & 15))) << 7) + (swz ^ 64);
  const char* LB0 = (const char*)&Bt[0][0] + ((((wn << 6) + (lane & 15))) << 7) + swz;
  const char* LB1 = (const char*)&Bt[0][0] + ((((wn << 6) + (lane & 15))) << 7) + (swz ^ 64);

  // ---- hoisted staging bases ----
  const int lrow8 = lane >> 3;             // row within 8-row staging group
  const int csrc  = (lane & 7) ^ lrow8;    // inverse-swizzled source chunk
  const ushort* gAw = A  + (size_t)(t0 + (wid << 4) + lrow8) * K + (csrc << 3);
  const ushort* gBw = Bw + (size_t)(d0 + (wid << 4) + lrow8) * K + (csrc << 3);
  char* stA = (char*)&At[0][0] + (wid << 11);   // wave-uniform LDS dest base
  char* stB = (char*)&Bt[0][0] + (wid << 11);

#define STAGE_A(T, BUF, H) do {                                                          \
    __builtin_amdgcn_global_load_lds(                                                    \
      (const __attribute__((address_space(1))) uint32_t*)(gAw + (size_t)((H)*128)*K + ((size_t)(T) << 6)),     \
      (__attribute__((address_space(3))) uint32_t*)(stA + (BUF)*32768 + (H)*16384), 16, 0, 0);                  \
    __builtin_amdgcn_global_load_lds(                                                    \
      (const __attribute__((address_space(1))) uint32_t*)(gAw + (size_t)((H)*128+8)*K + ((size_t)(T) << 6)),   \
      (__attribute__((address_space(3))) uint32_t*)(stA + (BUF)*32768 + (H)*16384 + 1024), 16, 0, 0);           \
  } while (0)
#define STAGE_B(T, BUF, H) do {                                                          \
    __builtin_amdgcn_global_load_lds(                                                    \
      (const __attribute__((address_space(1))) uint32_t*)(gBw + (size_t)((H)*128)*K + ((size_t)(T) << 6)),     \
      (__attribute__((address_space(3))) uint32_t*)(stB + (BUF)*32768 + (H)*16384), 16, 0, 0);                  \
    __builtin_amdgcn_global_load_lds(                                                    \
      (const __attribute__((address_space(1))) uint32_t*)(gBw + (size_t)((H)*128+8)*K + ((size_t)(T) << 6)),   \
      (__attribute__((address_space(3))) uint32_t*)(stB + (BUF)*32768 + (H)*16384 + 1024), 16, 0, 0);           \
  } while (0)

#define RD_A(dst, BASE, CUR, MH) do {                                                    \
    dst[0] = *(const bf16x8*)((BASE) + (CUR)*32768 + (MH)*8192 + 0);                     \
    dst[1] = *(const bf16x8*)((BASE) + (CUR)*32768 + (MH)*8192 + 2048);                  \
    dst[2] = *(const bf16x8*)((BASE) + (CUR)*32768 + (MH)*8192 + 4096);                  \
    dst[3] = *(const bf16x8*)((BASE) + (CUR)*32768 + (MH)*8192 + 6144);                  \
  } while (0)
#define RD_B(dst, BASE, CUR) do {                                                        \
    dst[0] = *(const bf16x8*)((BASE) + (CUR)*32768 + 0);                                 \
    dst[1] = *(const bf16x8*)((BASE) + (CUR)*32768 + 2048);                              \
    dst[2] = *(const bf16x8*)((BASE) + (CUR)*32768 + 4096);                              \
    dst[3] = *(const bf16x8*)((BASE) + (CUR)*32768 + 6144);                              \
  } while (0)
#define MFMA16(AF, BF, MH) do {                                                          \
    __builtin_amdgcn_s_setprio(1);                                                       \
    _Pragma("unroll")                                                                    \
    for (int m_ = 0; m_ < 4; ++m_)                                                       \
      _Pragma("unroll")                                                                  \
      for (int n_ = 0; n_ < 4; ++n_)                                                     \
        acc[((MH) << 2) + m_][n_] = __builtin_amdgcn_mfma_f32_16x16x32_bf16(             \
            AF[m_], BF[n_], acc[((MH) << 2) + m_][n_], 0, 0, 0);                         \
    __builtin_amdgcn_s_setprio(0);                                                       \
  } while (0)

#define TILE_BODY(T, CUR, HN1, HN2) do {                                                 \
    /* gate: tile T fully landed; B(T+1) may stay in flight */                           \
    if (HN1) { asm volatile("s_waitcnt vmcnt(4)" ::: "memory"); }                        \
    else     { asm volatile("s_waitcnt vmcnt(0)" ::: "memory"); }                        \
    __builtin_amdgcn_s_barrier();                                                        \
    /* ph1 */                                                                            \
    RD_A(aX, LA0, CUR, 0);                                                               \
    RD_B(b0f, LB0, CUR);                                                                 \
    if (HN1) { STAGE_A((T) + 1, (CUR) ^ 1, 0); STAGE_A((T) + 1, (CUR) ^ 1, 1); }         \
    MFMA16(aX, b0f, 0);                                                                  \
    /* ph2 */                                                                            \
    RD_A(aY, LA0, CUR, 1);                                                               \
    MFMA16(aY, b0f, 1);                                                                  \
    /* ph3 */                                                                            \
    RD_A(aX, LA1, CUR, 0);                                                               \
    RD_B(b1f, LB1, CUR);                                                                 \
    MFMA16(aX, b1f, 0);                                                                  \
    /* all waves' B reads of buf[CUR] returned (b1f consumed above) */                   \
    __builtin_amdgcn_s_barrier();                                                        \
    if (HN2) { STAGE_B((T) + 2, CUR, 0); STAGE_B((T) + 2, CUR, 1); }                     \
    /* ph4 (A-region reads; disjoint from B(t+2) writes) */                              \
    RD_A(aY, LA1, CUR, 1);                                                               \
    MFMA16(aY, b1f, 1);                                                                  \
  } while (0)

  constexpr int NT = K >> 6;   // even (256/1024 -> 4/16)

  // prologue: tile0 fully, tile1 B-halves (A(1) staged during tile 0 ph1)
  STAGE_A(0, 0, 0); STAGE_A(0, 0, 1);
  STAGE_B(0, 0, 0); STAGE_B(0, 0, 1);
  STAGE_B(1, 1, 0); STAGE_B(1, 1, 1);

  bf16x8 aX[4], aY[4], b0f[4], b1f[4];

#pragma unroll 1
  for (int tp = 0; tp < NT; tp += 2) {
    const bool m1 = (tp + 2 < NT);
    TILE_BODY(tp,     0, true, m1);
    TILE_BODY(tp + 1, 1, m1, m1);
  }

  // epilogue: C/D layout col = lane&15, row = (lane>>4)*4 + reg
  // m-outer / n-inner so the 4 chunks of each 128B line issue back-to-back.
  float bs[4];
#pragma unroll
  for (int n = 0; n < 4; ++n) bs[n] = bias[d0 + (wn << 6) + (n << 4) + (lane & 15)];
  float a0v = (EPI == 0) ? alpha[0] : 0.0f;
  float sA[4] = {0.f, 0.f, 0.f, 0.f}, s2A[4] = {0.f, 0.f, 0.f, 0.f};

#pragma unroll
  for (int m = 0; m < 8; ++m) {
#pragma unroll
    for (int r = 0; r < 4; ++r) {
      int row = t0 + (wm << 7) + (m << 4) + ((lane >> 4) << 2) + r;
      int orow = (EPI == 2) ? ((row & ~255) | inv[row]) : row;
#pragma unroll
      for (int n = 0; n < 4; ++n) {
        int d = d0 + (wn << 6) + (n << 4) + (lane & 15);
        float v = acc[m][n][r] + bs[n];
        if (EPI == 0) v = v > 0.f ? v : a0v * v;
        if (EPI == 1) { sA[n] += v; s2A[n] += v * v; }
        if (EPI == 2) ((float*)outp)[(size_t)orow * DOUT + d] = v;
        else          ((ushort*)outp)[(size_t)row * DOUT + d] = f2bf(v);
      }
    }
  }

  if (EPI == 1) {
    // deterministic per-block column reduction (256 cols), one slab row of partials.
    float2* sm = (float2*)&At[0][0];            // 8 x 256 float2 = 16KB
    int slot = (wm << 2) | (lane >> 4);         // 0..7
    __syncthreads();
#pragma unroll
    for (int n = 0; n < 4; ++n) {
      int c = (wn << 6) + (n << 4) + (lane & 15);
      sm[slot * 256 + c] = make_float2(sA[n], s2A[n]);
    }
    __syncthreads();
    if (tid < 256) {
      float ss = 0.f, ss2 = 0.f;
      for (int q = 0; q < 8; ++q) {
        float2 v = sm[q * 256 + tid];
        ss += v.x; ss2 += v.y;
      }
      part[(size_t)y * 2048 + d0 + tid]        = ss;
      part[(size_t)y * 2048 + 1024 + d0 + tid] = ss2;
    }
  }
#undef STAGE_A
#undef STAGE_B
#undef RD_A
#undef RD_B
#undef MFMA16
#undef TILE_BODY
}

// ------------------------------------------------------------ BN fold
__global__ void bnfold_kernel(const float* __restrict__ part, const float* __restrict__ g,
                              const float* __restrict__ bt, float* __restrict__ scsh) {
  int d = (blockIdx.x << 8) + threadIdx.x;    // grid 4
  float s = 0.f, s2 = 0.f;
  for (int j = 0; j < 128; ++j) { s += part[j * 2048 + d]; s2 += part[j * 2048 + 1024 + d]; }
  float mean = s * (1.f / 32768.f);
  float var  = s2 * (1.f / 32768.f) - mean * mean;
  float sc = g[d] * rsqrtf(var + 1e-5f);
  scsh[d] = sc;
  scsh[1024 + d] = bt[d] - mean * sc;
}

// y = prelu(y*sc + sh, p) [+ pos, prelu am], in place, 8 bf16/thread
template<bool MIX>
__global__ void bnact_kernel(ushort* __restrict__ Y, const float* __restrict__ scsh,
                             const float* __restrict__ p, const float* __restrict__ pos,
                             const float* __restrict__ am) {
  size_t i = (((size_t)blockIdx.x << 8) + threadIdx.x) << 3;
  int d = (int)(i & 1023);
  float pp = p[0];
  float aa = MIX ? am[0] : 0.f;
  float pv[8];
  if (MIX) {
    int prow = (int)((i >> 10) & 255);
    const float4* pb = (const float4*)(pos + ((size_t)prow << 10) + d);
    float4 pA = pb[0], pB = pb[1];
    pv[0]=pA.x; pv[1]=pA.y; pv[2]=pA.z; pv[3]=pA.w;
    pv[4]=pB.x; pv[5]=pB.y; pv[6]=pB.z; pv[7]=pB.w;
  }
  uint4 raw = *(const uint4*)(Y + i);
  uint32_t w[4] = {raw.x, raw.y, raw.z, raw.w};
  uint32_t o[4];
#pragma unroll
  for (int q = 0; q < 4; ++q) {
    int dd = d + q * 2;
    float v0 = bf2f(w[q] & 0xFFFFu) * scsh[dd]     + scsh[1024 + dd];
    float v1 = bf2f(w[q] >> 16)     * scsh[dd + 1] + scsh[1024 + dd + 1];
    v0 = v0 > 0.f ? v0 : pp * v0;
    v1 = v1 > 0.f ? v1 : pp * v1;
    if (MIX) {
      v0 += pv[2 * q];     v1 += pv[2 * q + 1];
      v0 = v0 > 0.f ? v0 : aa * v0;
      v1 = v1 > 0.f ? v1 : aa * v1;
    }
    o[q] = (uint32_t)f2bf(v0) | ((uint32_t)f2bf(v1) << 16);
  }
  *(uint4*)(Y + i) = make_uint4(o[0], o[1], o[2], o[3]);
}

// inverse permutation: inv[b, perm[b,i]] = i
__global__ void invperm_kernel(const int* __restrict__ perm, int* __restrict__ inv) {
  int t = (blockIdx.x << 8) + threadIdx.x;    // 32768
  inv[(t & ~255) + perm[t]] = t & 255;
}

// ----------------------------------------------------------- preprocessing
__global__ void f2b_kernel(const float* __restrict__ in, ushort* __restrict__ out, int n) {
  int i = (blockIdx.x << 8) + threadIdx.x;
  if (i < n) out[i] = f2bf(in[i]);
}

__global__ void padw0_kernel(const float* __restrict__ w0, ushort* __restrict__ o) {
  int d = blockIdx.x, j = threadIdx.x;  // 1024 x 256
  o[d * 256 + j] = (j < 147) ? f2bf(w0[d * 147 + j]) : (ushort)0;
}

// patch im2col (K padded to 256): P[t][j=cin*49+dy*7+dx] = x[b,cin,7pi+dy,7pj+dx]
__global__ void im2col_kernel(const float* __restrict__ x, ushort* __restrict__ P) {
  int t = blockIdx.x;        // 32768
  int j = threadIdx.x;       // 256
  ushort v = 0;
  if (j < 147) {
    int b = t >> 8, pidx = t & 255;
    int pi = pidx >> 4, pj = pidx & 15;
    int cin = j / 49, rem = j - cin * 49;
    int dy = rem / 7, dx = rem - dy * 7;
    v = f2bf(x[(size_t)(b * 3 + cin) * 12544 + (size_t)(pi * 7 + dy) * 112 + (pj * 7 + dx)]);
  }
  P[(size_t)t * 256 + j] = v;
}

extern "C" void kernel_launch(void* const* d_in, const int* in_sizes, int n_in,
                              void* d_out, int out_size, void* d_ws, size_t ws_size,
                              hipStream_t stream) {
  const float* x   = (const float*)d_in[0];
  const float* w0  = (const float*)d_in[1];
  const float* b0  = (const float*)d_in[2];
  const float* a0  = (const float*)d_in[3];
  const float* w1  = (const float*)d_in[4];
  const float* b1  = (const float*)d_in[5];
  const float* g1  = (const float*)d_in[6];
  const float* bt1 = (const float*)d_in[7];
  const float* p1  = (const float*)d_in[8];
  const float* w2  = (const float*)d_in[9];
  const float* b2  = (const float*)d_in[10];
  const float* g2  = (const float*)d_in[11];
  const float* bt2 = (const float*)d_in[12];
  const float* p2  = (const float*)d_in[13];
  const float* w3  = (const float*)d_in[14];
  const float* b3  = (const float*)d_in[15];
  const float* g3  = (const float*)d_in[16];
  const float* bt3 = (const float*)d_in[17];
  const float* p3  = (const float*)d_in[18];
  const float* pos = (const float*)d_in[19];
  const float* am  = (const float*)d_in[20];
  const float* wm  = (const float*)d_in[21];
  const float* bm  = (const float*)d_in[22];
  const int*  perm = (const int*)d_in[23];

  char* ws = (char*)d_ws;
  ushort* B0   = (ushort*)ws;                                   // 64MB
  ushort* B1   = (ushort*)(ws + 67108864);                      // 64MB
  float*  part = (float*)(ws + 134217728);                      // 128*2048*4 = 1MB (2MB rsvd)
  float*  scsh = (float*)(ws + 134217728 + 2097152);            // 8KB
  int*    inv  = (int*)  (ws + 134217728 + 2097152 + 8192);     // 128KB
  ushort* wbuf = (ushort*)(ws + 134217728 + 2097152 + 8192 + 131072); // 2MB

  invperm_kernel<<<dim3(128), dim3(256), 0, stream>>>(perm, inv);
  im2col_kernel<<<dim3(32768), dim3(256), 0, stream>>>(x, B1);
  padw0_kernel<<<dim3(1024), dim3(256), 0, stream>>>(w0, wbuf);

  // patch-embed conv as GEMM: P(B1) x w0^T -> act0(B0), bias+prelu  (K=256)
  gemm_kernel<0, 2, 256, 1024><<<dim3(512), dim3(512), 0, stream>>>(
      B1, wbuf, b0, a0, (void*)B0, nullptr, nullptr);

  // layer 1: B0 -> B1  (stats fused)
  f2b_kernel<<<dim3(4096), dim3(256), 0, stream>>>(w1, wbuf, 1048576);
  gemm_kernel<1, 2, 1024, 1024><<<dim3(512), dim3(512), 0, stream>>>(
      B0, wbuf, b1, nullptr, (void*)B1, part, nullptr);
  bnfold_kernel<<<dim3(4), dim3(256), 0, stream>>>(part, g1, bt1, scsh);
  bnact_kernel<false><<<dim3(16384), dim3(256), 0, stream>>>(B1, scsh, p1, nullptr, nullptr);

  // layer 2: B1 -> B0
  f2b_kernel<<<dim3(4096), dim3(256), 0, stream>>>(w2, wbuf, 1048576);
  gemm_kernel<1, 2, 1024, 1024><<<dim3(512), dim3(512), 0, stream>>>(
      B1, wbuf, b2, nullptr, (void*)B0, part, nullptr);
  bnfold_kernel<<<dim3(4), dim3(256), 0, stream>>>(part, g2, bt2, scsh);
  bnact_kernel<false><<<dim3(16384), dim3(256), 0, stream>>>(B0, scsh, p2, nullptr, nullptr);

  // layer 3: B0 -> B1, bnact fused with +pos & prelu(am)
  f2b_kernel<<<dim3(4096), dim3(256), 0, stream>>>(w3, wbuf, 1048576);
  gemm_kernel<1, 2, 1024, 1024><<<dim3(512), dim3(512), 0, stream>>>(
      B0, wbuf, b3, nullptr, (void*)B1, part, nullptr);
  bnfold_kernel<<<dim3(4), dim3(256), 0, stream>>>(part, g3, bt3, scsh);
  bnact_kernel<true><<<dim3(16384), dim3(256), 0, stream>>>(B1, scsh, p3, pos, am);

  // mixer: out = (enc @ wm^T + bm) rows scattered via inv -> d_out (fp32)
  f2b_kernel<<<dim3(2048), dim3(256), 0, stream>>>(wm, wbuf, 524288);
  gemm_kernel<2, 1, 1024, 512><<<dim3(256), dim3(512), 0, stream>>>(
      B1, wbuf, bm, nullptr, d_out, nullptr, inv);
}